// Round 3
// baseline (322.899 us; speedup 1.0000x reference)
//
#include <hip/hip_runtime.h>

#define T_STEPS 2000
#define BATCH   2048

typedef float v2f __attribute__((ext_vector_type(2)));

// ---------------------------------------------------------------------------
// Pass 1: X[t][c] = (sum_k a[k] * c[t-63+k][c] - b_act) / max_current
// 256-thread blocks, TT=32 rows/tile: halo refetch factor (32+63)/32 = 3.0.
// ---------------------------------------------------------------------------
#define CTT 32
__global__ __launch_bounds__(256) void conv_kernel(
    const float* __restrict__ currents, const float* __restrict__ a,
    const float* __restrict__ b_act, const float* __restrict__ max_current,
    float* __restrict__ X)
{
    int tid = threadIdx.x;
    int t0  = blockIdx.x * CTT;              // 63 t-tiles (last partial)
    int c   = blockIdx.y * 256 + tid;        // 8 col-tiles

    float inv = 1.0f / max_current[0];
    float cb  = -b_act[0] * inv;

    float cur[CTT + 63];
#pragma unroll
    for (int rr = 0; rr < CTT + 63; ++rr) {
        int r = t0 - 63 + rr;
        cur[rr] = (r >= 0 && r < T_STEPS) ? currents[(long)r * BATCH + c] : 0.0f;
    }
#pragma unroll
    for (int i = 0; i < CTT; ++i) {
        int t = t0 + i;
        if (t < T_STEPS) {
            float acc = 0.0f;
#pragma unroll
            for (int k = 0; k < 64; ++k)
                acc = fmaf(a[k], cur[i + k], acc);
            X[(long)t * BATCH + c] = fmaf(acc, inv, cb);
        }
    }
}

// ---------------------------------------------------------------------------
// Pass 2: serial recurrence, ring fully IN-LANE. 1 lane = 1 column.
// Per lane: 64 ring regs; ring[r] at phase phi holds the partial sum for the
// step completing at phase r (mod 64): born with X[t_complete], then receives
// tapv[d-1]*f for each of the 64 steps before completion (d = steps-to-go).
//   tapv[m] = (1000/mc) * b_lag[63-m]   (lag d coefficient = b_lag[64-d])
// Per step (phase phi, t = 64*ch + phi):
//   u = ring[phi]                     (complete: X_t + sum_j g_j f_{t-j})
//   f = relu(M*tanh(poly(u)))         (all in-lane)
//   store f; ring[phi] = X[t+64]      (rebirth as position 63)
//   ring[(phi+d)&63] += tapv[d-1]*f   for d=1..64  -> 32 v_pk_fma_f32
// Pair alignment: ring pair k=(2k,2k+1) needs taps starting at (2k-1-phi)&63.
// Two tap copies: TA[j]={tv[2j],tv[2j+1]} (even start, phi odd),
// TB[j]={tv[(2j+1)&63],tv[(2j+2)&63]} (odd start incl. wrap pair, phi even).
// Zero cross-lane ops anywhere in the chain.
// ---------------------------------------------------------------------------
__global__ __launch_bounds__(64) void rec_kernel(
    const float* X,                       // == out (scratch from pass 1)
    const float* __restrict__ b_lag, const float* __restrict__ poly_coeff,
    const float* __restrict__ max_current, const float* __restrict__ max_firing_rate,
    float* out)
{
    int lane = threadIdx.x;
    long col = (long)blockIdx.x * 64 + lane;

    float inv = 1.0f / max_current[0];
    float g   = 1000.0f * inv;

    v2f TA[32], TB[32];
#pragma unroll
    for (int j = 0; j < 32; ++j) {
        // tv[m] = g * b_lag[63 - m]
        TA[j] = (v2f){ g * b_lag[63 - 2*j], g * b_lag[62 - 2*j] };
        int m1 = (2*j + 1) & 63, m2i = (2*j + 2) & 63;
        TB[j] = (v2f){ g * b_lag[63 - m1], g * b_lag[63 - m2i] };
    }

    // tanh(p) = 1 - 2/(exp2(K2*p)+1); K2 = 2*log2(e) folded into squared coeffs.
    const float K2 = 2.8853900817779268f;
    float c0 = poly_coeff[0], c1 = poly_coeff[1], c2 = poly_coeff[2], c3 = poly_coeff[3];
    float k0 = K2*c0*c0, k1 = K2*c1*c1, k2 = K2*c2*c2, k3 = K2*c3*c3;
    float M  = max_firing_rate[0];
    float m2 = -2.0f * M;

    auto act = [&](float u) -> float {
        float u2 = u * u;                       // Estrin, depth 2
        float a1 = fmaf(u, k1, k0);
        float a2 = fmaf(u, k3, k2);
        float p  = fmaf(u2, a2, a1);
        float e  = __builtin_amdgcn_exp2f(p);
        float r_ = __builtin_amdgcn_rcpf(e + 1.0f);
        return fmaxf(fmaf(m2, r_, M), 0.0f);    // relu(M*tanh), overflow-free
    };

    v2f R[32];
#pragma unroll
    for (int r = 0; r < 64; ++r)                // slots for steps 0..63: born = X_t
        R[r >> 1][r & 1] = X[(long)r * BATCH + col];

    float xc[8], xn[8];
#pragma unroll
    for (int i = 0; i < 8; ++i)                 // future-X for phases 0..7 of chunk 0
        xc[i] = X[(long)(64 + i) * BATCH + col];

    for (int ch = 0; ch < 31; ++ch) {           // 31 full chunks: t = 0..1983
        long t0 = (long)ch * 64;
#pragma unroll
        for (int gph = 0; gph < 8; ++gph) {
            // prefetch next group's future-X (consumed 8 steps from now)
            long tf = t0 + 64 + (long)(gph + 1) * 8;
            if (tf + 7 < T_STEPS) {
#pragma unroll
                for (int i = 0; i < 8; ++i) xn[i] = X[(tf + i) * BATCH + col];
            } else {
#pragma unroll
                for (int i = 0; i < 8; ++i)
                    xn[i] = (tf + i < T_STEPS) ? X[(tf + i) * BATCH + col] : 0.0f;
            }
#pragma unroll
            for (int i = 0; i < 8; ++i) {
                const int phi = gph * 8 + i;            // compile-time
                float u = R[phi >> 1][phi & 1];
                float f = act(u);
                out[(t0 + phi) * BATCH + col] = f;
                R[phi >> 1][phi & 1] = xc[i];           // rebirth: X[t+64]
                v2f ff = (v2f){ f, f };
                if (phi & 1) {
                    const int off = (phi + 1) >> 1;     // TA[(k - (phi+1)/2) & 31]
#pragma unroll
                    for (int k = 0; k < 32; ++k)
                        R[k] = __builtin_elementwise_fma(TA[(k - off) & 31], ff, R[k]);
                } else {
                    const int off = 1 + (phi >> 1);     // TB[(k - 1 - phi/2) & 31]
#pragma unroll
                    for (int k = 0; k < 32; ++k)
                        R[k] = __builtin_elementwise_fma(TB[(k - off) & 31], ff, R[k]);
                }
            }
#pragma unroll
            for (int i = 0; i < 8; ++i) xc[i] = xn[i];  // rotate prefetch buffer
        }
    }

    // tail: 16 steps, t = 1984..1999. No rebirth/prefetch; taps still needed
    // (later tail steps consume earlier tail f's).
#pragma unroll
    for (int phi = 0; phi < 16; ++phi) {
        float u = R[phi >> 1][phi & 1];
        float f = act(u);
        out[(long)(1984 + phi) * BATCH + col] = f;
        v2f ff = (v2f){ f, f };
        if (phi & 1) {
            const int off = (phi + 1) >> 1;
#pragma unroll
            for (int k = 0; k < 32; ++k)
                R[k] = __builtin_elementwise_fma(TA[(k - off) & 31], ff, R[k]);
        } else {
            const int off = 1 + (phi >> 1);
#pragma unroll
            for (int k = 0; k < 32; ++k)
                R[k] = __builtin_elementwise_fma(TB[(k - off) & 31], ff, R[k]);
        }
    }
}

extern "C" void kernel_launch(void* const* d_in, const int* in_sizes, int n_in,
                              void* d_out, int out_size, void* d_ws, size_t ws_size,
                              hipStream_t stream) {
    const float* currents   = (const float*)d_in[0];
    const float* a          = (const float*)d_in[1];
    const float* b_lag      = (const float*)d_in[2];
    const float* poly_coeff = (const float*)d_in[3];
    const float* b_act      = (const float*)d_in[4];
    const float* mc         = (const float*)d_in[5];
    const float* mfr        = (const float*)d_in[6];
    float* out = (float*)d_out;

    // Pass 1: conv + bias + 1/mc folded -> X, staged in `out`.
    conv_kernel<<<dim3((T_STEPS + CTT - 1) / CTT, BATCH / 256), 256, 0, stream>>>(
        currents, a, b_act, mc, out);
    // Pass 2: in-lane serial recurrence, 64 columns/wave, 32 single-wave blocks.
    rec_kernel<<<BATCH / 64, 64, 0, stream>>>(out, b_lag, poly_coeff, mc, mfr, out);
}